// Round 3
// baseline (390.160 us; speedup 1.0000x reference)
//
#include <hip/hip_runtime.h>
#include <hip/hip_bf16.h>
#include <hip/hip_fp16.h>

// Problem constants (GuidedSampler): B=32, DIM=512, H=64, W=64, K=64, DQ=3
#define BN   32
#define DIMK 512
#define HW   4096
#define KK   64
#define DQ   3
#define RR   192            // KK*DQ GEMM rows
#define NT   128            // hw columns per block
#define NBLK (HW / NT)      // 32

typedef _Float16 half8  __attribute__((ext_vector_type(8)));
typedef float    f32x2  __attribute__((ext_vector_type(2)));
typedef float    f32x4  __attribute__((ext_vector_type(4)));
typedef short    short8 __attribute__((ext_vector_type(8)));

// Workspace layout
#define A16_OFF    0
#define A16_BYTES  (RR * DIMK * 2)                   // 196608: W as fp16 [R][DIM]
#define PART_OFF   196608
#define PART_BYTES (BN * NBLK * KK * 4)              // 262144: per-block dist partials
#define KV_OFF     524288
#define KV_BYTES   ((size_t)BN * RR * HW * 2)        // 50331648 (kv as bf16)

#define OUT_SEL    ((size_t)BN * DQ * HW)            // codes offset in out
#define OUT_LOSS   (OUT_SEL + BN)

// ---------------------------------------------------------------------------
// Kernel 1: W fp32 -> fp16 (L2-resident thereafter), zero the loss slot.
// (ws/out are re-poisoned 0xAA before every timed launch -> re-init each call)
__global__ void init_kernel(const float* __restrict__ Wsrc,
                            _Float16* __restrict__ A16,
                            float* __restrict__ out) {
  int gid = blockIdx.x * 256 + threadIdx.x;
  if (gid < RR * DIMK) A16[gid] = (_Float16)Wsrc[gid];
  if (gid == 0)        out[OUT_LOSS] = 0.f;
}

// ---------------------------------------------------------------------------
// Kernel 2: per (b, hw-tile): C[192][128] = W_f16(192x512) * f(512x128).
// A fragments load DIRECTLY from global (L2-resident, 16B/lane coalesced,
// register-prefetched 1 iter ahead) -- no A LDS. B is LDS double-buffered
// (transposed [kblk][n][kin8] so frag reads are contiguous ds_read_b128);
// ONE barrier per K-iter, B prefetch lands in VGPRs so no vmcnt(0) drain.
// Stores kv bf16, writes per-block dist partials (no atomics).
// MFMA 16x16x32 f16 layouts (m89/m91 family):
//   A[m=lane&15][k=quad*8+j], B[k=quad*8+j][n=lane&15], C: col=lane&15,row=quad*4+reg
template <bool STORE>
__global__ __launch_bounds__(256) void gemm_dist_kernel(
    const float* __restrict__ f, const float* __restrict__ query,
    const _Float16* __restrict__ A16, __hip_bfloat16* __restrict__ kv,
    float* __restrict__ partial) {
  __shared__ __align__(16) _Float16 Blds[2][4][NT][8];    // 16384 B
  __shared__ float qlds[DQ][NT];                          // 1536 B
  __shared__ float rowsum[RR];                            // 768 B

  const int t  = threadIdx.x;
  const int w  = t >> 6;        // wave id: rows [48w, 48w+48)
  const int l  = t & 63;
  const int lq = l >> 4;        // quad
  const int ln = l & 15;
  const int b  = blockIdx.y;
  const int n0 = blockIdx.x * NT;

  for (int s = t; s < DQ * NT; s += 256) {
    int q = s / NT, n = s % NT;
    qlds[q][n] = query[((size_t)b * DQ + q) * HW + n0 + n];
  }

  f32x4 acc[3][8];
#pragma unroll
  for (int mt = 0; mt < 3; mt++)
#pragma unroll
    for (int nt = 0; nt < 8; nt++) acc[mt][nt] = (f32x4)0.f;

  // B staging decomposition: thread = (col-pair bn -> cols 2bn,2bn+1; k-octet bkb)
  const int bn  = t & 63;
  const int bkb = t >> 6;       // 0..3 -> k rows [8*bkb, 8*bkb+8)

  f32x2 bpre[8];     // B prefetch regs (fp32 pairs, converted at stage time)
  half8 apre[3];     // A fragment prefetch regs (direct from L2)

  const int arow = w * 48 + ln; // this lane's A row base (mt adds 16)

  auto loadB = [&](int kk) {
    const float* fp = f + ((size_t)b * DIMK + kk * 32 + bkb * 8) * HW + n0 + 2 * bn;
#pragma unroll
    for (int j = 0; j < 8; j++) bpre[j] = *(const f32x2*)&fp[(size_t)j * HW];
  };
  auto loadA = [&](int kk) {
#pragma unroll
    for (int mt = 0; mt < 3; mt++)
      apre[mt] = *(const half8*)&A16[(arow + mt * 16) * DIMK + kk * 32 + lq * 8];
  };
  auto stageB = [&](int buf) {
    half8 h0, h1;
#pragma unroll
    for (int j = 0; j < 8; j++) {
      h0[j] = (_Float16)bpre[j][0];
      h1[j] = (_Float16)bpre[j][1];
    }
    *(half8*)&Blds[buf][bkb][2 * bn][0]     = h0;   // 32B/lane stride: 2-way, free
    *(half8*)&Blds[buf][bkb][2 * bn + 1][0] = h1;
  };

  loadA(0);
  loadB(0);
  stageB(0);
  for (int kk = 0; kk < DIMK / 32; kk++) {
    const int cur = kk & 1;
    __syncthreads();                       // buf[cur] ready; buf[cur^1] free
    if (kk < DIMK / 32 - 1) loadB(kk + 1); // HBM loads in flight across MFMAs

    half8 af[3];
#pragma unroll
    for (int mt = 0; mt < 3; mt++) af[mt] = apre[mt];
    if (kk < DIMK / 32 - 1) loadA(kk + 1); // L2 loads in flight across MFMAs

#pragma unroll
    for (int h = 0; h < 2; h++) {          // split nt to cap live bf regs
      half8 bf[4];
#pragma unroll
      for (int n4 = 0; n4 < 4; n4++)
        bf[n4] = *(const half8*)&Blds[cur][lq][h * 64 + n4 * 16 + ln][0];
#pragma unroll
      for (int mt = 0; mt < 3; mt++)
#pragma unroll
        for (int n4 = 0; n4 < 4; n4++)
          acc[mt][h * 4 + n4] = __builtin_amdgcn_mfma_f32_16x16x32_f16(
              af[mt], bf[n4], acc[mt][h * 4 + n4], 0, 0, 0);
    }
    if (kk < DIMK / 32 - 1) stageB(cur ^ 1);
  }

  // Epilogue: kv store + per-row sq-diff partials
  float rs[3][4];
#pragma unroll
  for (int mt = 0; mt < 3; mt++)
#pragma unroll
    for (int i = 0; i < 4; i++) rs[mt][i] = 0.f;

#pragma unroll
  for (int mt = 0; mt < 3; mt++) {
#pragma unroll
    for (int i = 0; i < 4; i++) {
      int r = w * 48 + mt * 16 + lq * 4 + i;   // global row 0..191
      int q = r % 3;
#pragma unroll
      for (int nt = 0; nt < 8; nt++) {
        int n = nt * 16 + ln;
        float c = acc[mt][nt][i];
        if (STORE) kv[((size_t)b * RR + r) * HW + n0 + n] = __float2bfloat16(c);
        float d = c - qlds[q][n];
        rs[mt][i] += d * d;
      }
    }
  }
  // butterfly over low 4 lane bits (sums the 16 columns within a quad)
#pragma unroll
  for (int mt = 0; mt < 3; mt++)
#pragma unroll
    for (int i = 0; i < 4; i++) {
      float v = rs[mt][i];
      v += __shfl_xor(v, 1, 64);
      v += __shfl_xor(v, 2, 64);
      v += __shfl_xor(v, 4, 64);
      v += __shfl_xor(v, 8, 64);
      rs[mt][i] = v;
    }
  if (ln < 12) {
    int mt = ln >> 2, i = ln & 3;
    rowsum[w * 48 + mt * 16 + lq * 4 + i] = rs[mt][i];
  }
  __syncthreads();
  if (t < KK)
    partial[((size_t)b * NBLK + blockIdx.x) * KK + t] =
        rowsum[3 * t] + rowsum[3 * t + 1] + rowsum[3 * t + 2];
}

// ---------------------------------------------------------------------------
// Kernel 3a (STORE path): sum partials, argmin, write codes, gather, loss
__global__ __launch_bounds__(256) void gather_kernel(
    const __hip_bfloat16* __restrict__ kv, const float* __restrict__ query,
    const float* __restrict__ partial, float* __restrict__ out) {
  int b = blockIdx.x, t = threadIdx.x;
  __shared__ float dsum[KK];
  __shared__ int scode;
  __shared__ float red[4];
  if (t < KK) {
    float s = 0.f;
    for (int x = 0; x < NBLK; x++) s += partial[((size_t)b * NBLK + x) * KK + t];
    dsum[t] = s;
  }
  __syncthreads();
  if (t == 0) {
    float best = dsum[0]; int bi = 0;
    for (int k = 1; k < KK; k++)
      if (dsum[k] < best) { best = dsum[k]; bi = k; }  // strict < (jnp.argmin)
    scode = bi;
    out[OUT_SEL + b] = (float)bi;                      // codes chunk, as float
  }
  __syncthreads();
  int code = scode;
  const short8* src = (const short8*)(kv + ((size_t)b * RR + code * DQ) * HW);
  const f32x4*  qp  = (const f32x4*)(query + (size_t)b * DQ * HW);
  f32x4*        op  = (f32x4*)(out + (size_t)b * DQ * HW);
  float lsum = 0.f;
  for (int c = t; c < DQ * HW / 8; c += 256) {   // 1536 short8 chunks
    short8 v = src[c];
    f32x4 o0, o1;
#pragma unroll
    for (int j = 0; j < 4; j++) {
      unsigned u0 = ((unsigned)(unsigned short)v[j]) << 16;
      unsigned u1 = ((unsigned)(unsigned short)v[4 + j]) << 16;
      o0[j] = __builtin_bit_cast(float, u0);
      o1[j] = __builtin_bit_cast(float, u1);
    }
    f32x4 q0 = qp[2 * c], q1 = qp[2 * c + 1];
    op[2 * c] = o0; op[2 * c + 1] = o1;
#pragma unroll
    for (int j = 0; j < 4; j++) {
      float d0 = o0[j] - q0[j], d1 = o1[j] - q1[j];
      lsum += d0 * d0 + d1 * d1;
    }
  }
  for (int off = 1; off < 64; off <<= 1) lsum += __shfl_xor(lsum, off, 64);
  if ((t & 63) == 0) red[t >> 6] = lsum;
  __syncthreads();
  if (t == 0)
    atomicAdd(&out[OUT_LOSS],
              (red[0] + red[1] + red[2] + red[3]) * (1.f / (float)(BN * DQ * HW)));
}

// ---------------------------------------------------------------------------
// Kernel 3b (fallback if ws too small): recompute selected kv from features
__global__ __launch_bounds__(256) void recompute_kernel(
    const float* __restrict__ f, const float* __restrict__ query,
    const float* __restrict__ Wsrc, const float* __restrict__ partial,
    float* __restrict__ out) {
  int b = blockIdx.y, t = threadIdx.x;
  int hw = blockIdx.x * 256 + t;
  __shared__ float dsum[KK];
  __shared__ int scode;
  __shared__ float red[4];
  if (t < KK) {
    float s = 0.f;
    for (int x = 0; x < NBLK; x++) s += partial[((size_t)b * NBLK + x) * KK + t];
    dsum[t] = s;
  }
  __syncthreads();
  if (t == 0) {
    float best = dsum[0]; int bi = 0;
    for (int k = 1; k < KK; k++)
      if (dsum[k] < best) { best = dsum[k]; bi = k; }
    scode = bi;
    if (blockIdx.x == 0) out[OUT_SEL + b] = (float)bi;
  }
  __syncthreads();
  int code = scode;
  const float* w0 = Wsrc + (size_t)code * DQ * DIMK;
  const float* fp = f + (size_t)b * DIMK * HW + hw;
  float a0 = 0.f, a1 = 0.f, a2 = 0.f;
  for (int d = 0; d < DIMK; d++) {
    float fv = fp[(size_t)d * HW];
    a0 += w0[d] * fv;
    a1 += w0[DIMK + d] * fv;
    a2 += w0[2 * DIMK + d] * fv;
  }
  const float* qp = query + (size_t)b * DQ * HW;
  float* op = out + (size_t)b * DQ * HW;
  op[hw] = a0; op[HW + hw] = a1; op[2 * HW + hw] = a2;
  float d0 = a0 - qp[hw], d1 = a1 - qp[HW + hw], d2 = a2 - qp[2 * HW + hw];
  float lsum = d0 * d0 + d1 * d1 + d2 * d2;
  for (int off = 1; off < 64; off <<= 1) lsum += __shfl_xor(lsum, off, 64);
  if ((t & 63) == 0) red[t >> 6] = lsum;
  __syncthreads();
  if (t == 0)
    atomicAdd(&out[OUT_LOSS],
              (red[0] + red[1] + red[2] + red[3]) * (1.f / (float)(BN * DQ * HW)));
}

extern "C" void kernel_launch(void* const* d_in, const int* in_sizes, int n_in,
                              void* d_out, int out_size, void* d_ws, size_t ws_size,
                              hipStream_t stream) {
  const float* f     = (const float*)d_in[0];
  const float* query = (const float*)d_in[1];
  const float* Wsrc  = (const float*)d_in[2];
  float* out = (float*)d_out;
  char*  ws  = (char*)d_ws;

  _Float16*        A16     = (_Float16*)(ws + A16_OFF);
  float*           partial = (float*)(ws + PART_OFF);
  __hip_bfloat16*  kv      = (__hip_bfloat16*)(ws + KV_OFF);

  // Deterministic host-side branch (same every call -> graph-capture safe)
  const bool store = ws_size >= (size_t)KV_OFF + KV_BYTES;

  init_kernel<<<384, 256, 0, stream>>>(Wsrc, A16, out);
  if (store) {
    gemm_dist_kernel<true><<<dim3(NBLK, BN), 256, 0, stream>>>(f, query, A16, kv, partial);
    gather_kernel<<<BN, 256, 0, stream>>>(kv, query, partial, out);
  } else {
    gemm_dist_kernel<false><<<dim3(NBLK, BN), 256, 0, stream>>>(f, query, A16, nullptr, partial);
    recompute_kernel<<<dim3(HW / 256, BN), 256, 0, stream>>>(f, query, Wsrc, partial, out);
  }
}

// Round 4
// 382.166 us; speedup vs baseline: 1.0209x; 1.0209x over previous
//
#include <hip/hip_runtime.h>
#include <hip/hip_bf16.h>
#include <hip/hip_fp16.h>

// Problem constants (GuidedSampler): B=32, DIM=512, H=64, W=64, K=64, DQ=3
#define BN   32
#define DIMK 512
#define HW   4096
#define KK   64
#define DQ   3
#define RR   192            // KK*DQ GEMM rows
#define NT   128            // hw columns per block
#define NBLK (HW / NT)      // 32
#define KITER (DIMK / 32)   // 16

typedef _Float16 half8  __attribute__((ext_vector_type(8)));
typedef float    f32x2  __attribute__((ext_vector_type(2)));
typedef float    f32x4  __attribute__((ext_vector_type(4)));
typedef short    short8 __attribute__((ext_vector_type(8)));

// Workspace layout
#define A16_OFF    0
#define A16_BYTES  (RR * DIMK * 2)                   // 196608: W as fp16 [R][DIM]
#define PART_OFF   196608
#define PART_BYTES (BN * NBLK * KK * 4)              // 262144: per-block dist partials
#define KV_OFF     524288
#define KV_BYTES   ((size_t)BN * RR * HW * 2)        // 50331648 (kv as bf16)

#define OUT_SEL    ((size_t)BN * DQ * HW)            // codes offset in out
#define OUT_LOSS   (OUT_SEL + BN)

// ---------------------------------------------------------------------------
// Kernel 1: W fp32 -> fp16 (L2-resident thereafter), zero the loss slot.
// (ws/out are re-poisoned 0xAA before every timed launch -> re-init each call)
__global__ void init_kernel(const float* __restrict__ Wsrc,
                            _Float16* __restrict__ A16,
                            float* __restrict__ out) {
  int gid = blockIdx.x * 256 + threadIdx.x;
  if (gid < RR * DIMK) A16[gid] = (_Float16)Wsrc[gid];
  if (gid == 0)        out[OUT_LOSS] = 0.f;
}

// ---------------------------------------------------------------------------
// Kernel 2: per (b, hw-tile): C[192][128] = W_f16(192x512) * f(512x128).
// A staged via LDS (double-buffered, 1-deep register prefetch from L2).
// B staged via LDS (double-buffered, TWO-deep register prefetch from HBM:
// latency budget ~1.8 iters vs ~900cyc HBM). ONE barrier per K-iter; all
// prefetch lands in VGPRs so the barrier needs no vmcnt(0) drain. vmcnt
// queue order per iter is [A(L2) x3, B(HBM) x8] so staging waits leave the
// deep B prefetch in flight. Stores kv bf16, writes per-block dist partials.
// MFMA 16x16x32 f16 layouts (m89/m91 family):
//   A[m=lane&15][k=quad*8+j], B[k=quad*8+j][n=lane&15], C: col=lane&15,row=quad*4+reg
template <bool STORE>
__global__ __launch_bounds__(256) void gemm_dist_kernel(
    const float* __restrict__ f, const float* __restrict__ query,
    const _Float16* __restrict__ A16, __hip_bfloat16* __restrict__ kv,
    float* __restrict__ partial) {
  // A rows padded to 40 halfs (80 B: 16B-aligned rows, spreads banks)
  __shared__ __align__(16) _Float16 Alds[2][RR][40];      // 30720 B
  __shared__ __align__(16) _Float16 Blds[2][4][NT][8];    // 16384 B
  __shared__ float qlds[DQ][NT];                          // 1536 B
  __shared__ float rowsum[RR];                            // 768 B

  const int t  = threadIdx.x;
  const int w  = t >> 6;        // wave id: rows [48w, 48w+48)
  const int l  = t & 63;
  const int lq = l >> 4;        // quad
  const int ln = l & 15;
  const int b  = blockIdx.y;
  const int n0 = blockIdx.x * NT;

  for (int s = t; s < DQ * NT; s += 256) {
    int q = s / NT, n = s % NT;
    qlds[q][n] = query[((size_t)b * DQ + q) * HW + n0 + n];
  }

  f32x4 acc[3][8];
#pragma unroll
  for (int mt = 0; mt < 3; mt++)
#pragma unroll
    for (int nt = 0; nt < 8; nt++) acc[mt][nt] = (f32x4)0.f;

  // B staging decomposition: thread = (col-pair bn -> cols 2bn,2bn+1; k-octet bkb)
  const int bn  = t & 63;
  const int bkb = t >> 6;       // 0..3 -> k rows [8*bkb, 8*bkb+8)

  f32x2 set0[8], set1[8];  // B prefetch ping-pong register sets
  half8 apre[3];           // A fragment prefetch regs (L2)

  auto loadB = [&](int kk, f32x2 (&dst)[8]) {
    const float* fp = f + ((size_t)b * DIMK + kk * 32 + bkb * 8) * HW + n0 + 2 * bn;
#pragma unroll
    for (int j = 0; j < 8; j++) dst[j] = *(const f32x2*)&fp[(size_t)j * HW];
  };
  auto loadA = [&](int kk) {
#pragma unroll
    for (int i = 0; i < 3; i++) {
      int s = t + i * 256;
      int m = s >> 2, oct = s & 3;
      apre[i] = *(const half8*)&A16[m * DIMK + kk * 32 + oct * 8];
    }
  };
  auto stageA = [&](int buf) {
#pragma unroll
    for (int i = 0; i < 3; i++) {
      int s = t + i * 256;
      int m = s >> 2, oct = s & 3;
      *(half8*)&Alds[buf][m][oct * 8] = apre[i];
    }
  };
  auto stageB = [&](const f32x2 (&src)[8], int buf) {
    half8 h0, h1;
#pragma unroll
    for (int j = 0; j < 8; j++) {
      h0[j] = (_Float16)src[j][0];
      h1[j] = (_Float16)src[j][1];
    }
    *(half8*)&Blds[buf][bkb][2 * bn][0]     = h0;  // 32B/lane stride: 2-way, free
    *(half8*)&Blds[buf][bkb][2 * bn + 1][0] = h1;
  };

  // Preamble: fill prefetch pipeline (queue: [B0 x8, A0 x3, B1 x8])
  loadB(0, set0);
  loadA(0);
  loadB(1, set1);
  stageA(0);          // waits A0 (vmcnt 8: B1 stays in flight)
  stageB(set0, 0);    // B0 already drained by the A wait

  // iter kk: SA = set reloaded (kk+2), SB = set staged for kk+1
  auto iter = [&](int kk, f32x2 (&SA)[8], const f32x2 (&SB)[8]) {
    const int cur = kk & 1;
    __syncthreads();                        // buf[cur] ready; buf[cur^1] free
    if (kk < KITER - 1) loadA(kk + 1);      // L2, issued FIRST (shallow wait)
    if (kk < KITER - 2) loadB(kk + 2, SA);  // HBM, stays in flight past stages

    half8 af[3];
#pragma unroll
    for (int mt = 0; mt < 3; mt++)
      af[mt] = *(const half8*)&Alds[cur][w * 48 + mt * 16 + ln][lq * 8];

#pragma unroll
    for (int h = 0; h < 2; h++) {           // split nt to cap live bf regs
      half8 bf[4];
#pragma unroll
      for (int n4 = 0; n4 < 4; n4++)
        bf[n4] = *(const half8*)&Blds[cur][lq][h * 64 + n4 * 16 + ln][0];
#pragma unroll
      for (int mt = 0; mt < 3; mt++)
#pragma unroll
        for (int n4 = 0; n4 < 4; n4++)
          acc[mt][h * 4 + n4] = __builtin_amdgcn_mfma_f32_16x16x32_f16(
              af[mt], bf[n4], acc[mt][h * 4 + n4], 0, 0, 0);
    }
    if (kk < KITER - 1) {
      stageA(cur ^ 1);      // waits this iter's A (vmcnt 8)
      stageB(SB, cur ^ 1);  // SB loaded ~1.8 iters ago: no extra wait
    }
  };

  for (int kk2 = 0; kk2 < KITER / 2; kk2++) {
    iter(2 * kk2,     set0, set1);
    iter(2 * kk2 + 1, set1, set0);
  }

  // Epilogue: kv store + per-row sq-diff partials
  float rs[3][4];
#pragma unroll
  for (int mt = 0; mt < 3; mt++)
#pragma unroll
    for (int i = 0; i < 4; i++) rs[mt][i] = 0.f;

#pragma unroll
  for (int mt = 0; mt < 3; mt++) {
#pragma unroll
    for (int i = 0; i < 4; i++) {
      int r = w * 48 + mt * 16 + lq * 4 + i;   // global row 0..191
      int q = r % 3;
#pragma unroll
      for (int nt = 0; nt < 8; nt++) {
        int n = nt * 16 + ln;
        float c = acc[mt][nt][i];
        if (STORE) kv[((size_t)b * RR + r) * HW + n0 + n] = __float2bfloat16(c);
        float d = c - qlds[q][n];
        rs[mt][i] += d * d;
      }
    }
  }
  // butterfly over low 4 lane bits (sums the 16 columns within a quad)
#pragma unroll
  for (int mt = 0; mt < 3; mt++)
#pragma unroll
    for (int i = 0; i < 4; i++) {
      float v = rs[mt][i];
      v += __shfl_xor(v, 1, 64);
      v += __shfl_xor(v, 2, 64);
      v += __shfl_xor(v, 4, 64);
      v += __shfl_xor(v, 8, 64);
      rs[mt][i] = v;
    }
  if (ln < 12) {
    int mt = ln >> 2, i = ln & 3;
    rowsum[w * 48 + mt * 16 + lq * 4 + i] = rs[mt][i];
  }
  __syncthreads();
  if (t < KK)
    partial[((size_t)b * NBLK + blockIdx.x) * KK + t] =
        rowsum[3 * t] + rowsum[3 * t + 1] + rowsum[3 * t + 2];
}

// ---------------------------------------------------------------------------
// Kernel 3a (STORE path): sum partials, argmin, write codes, gather, loss
__global__ __launch_bounds__(256) void gather_kernel(
    const __hip_bfloat16* __restrict__ kv, const float* __restrict__ query,
    const float* __restrict__ partial, float* __restrict__ out) {
  int b = blockIdx.x, t = threadIdx.x;
  __shared__ float dsum[KK];
  __shared__ int scode;
  __shared__ float red[4];
  if (t < KK) {
    float s = 0.f;
    for (int x = 0; x < NBLK; x++) s += partial[((size_t)b * NBLK + x) * KK + t];
    dsum[t] = s;
  }
  __syncthreads();
  if (t == 0) {
    float best = dsum[0]; int bi = 0;
    for (int k = 1; k < KK; k++)
      if (dsum[k] < best) { best = dsum[k]; bi = k; }  // strict < (jnp.argmin)
    scode = bi;
    out[OUT_SEL + b] = (float)bi;                      // codes chunk, as float
  }
  __syncthreads();
  int code = scode;
  const short8* src = (const short8*)(kv + ((size_t)b * RR + code * DQ) * HW);
  const f32x4*  qp  = (const f32x4*)(query + (size_t)b * DQ * HW);
  f32x4*        op  = (f32x4*)(out + (size_t)b * DQ * HW);
  float lsum = 0.f;
  for (int c = t; c < DQ * HW / 8; c += 256) {   // 1536 short8 chunks
    short8 v = src[c];
    f32x4 o0, o1;
#pragma unroll
    for (int j = 0; j < 4; j++) {
      unsigned u0 = ((unsigned)(unsigned short)v[j]) << 16;
      unsigned u1 = ((unsigned)(unsigned short)v[4 + j]) << 16;
      o0[j] = __builtin_bit_cast(float, u0);
      o1[j] = __builtin_bit_cast(float, u1);
    }
    f32x4 q0 = qp[2 * c], q1 = qp[2 * c + 1];
    op[2 * c] = o0; op[2 * c + 1] = o1;
#pragma unroll
    for (int j = 0; j < 4; j++) {
      float d0 = o0[j] - q0[j], d1 = o1[j] - q1[j];
      lsum += d0 * d0 + d1 * d1;
    }
  }
  for (int off = 1; off < 64; off <<= 1) lsum += __shfl_xor(lsum, off, 64);
  if ((t & 63) == 0) red[t >> 6] = lsum;
  __syncthreads();
  if (t == 0)
    atomicAdd(&out[OUT_LOSS],
              (red[0] + red[1] + red[2] + red[3]) * (1.f / (float)(BN * DQ * HW)));
}

// ---------------------------------------------------------------------------
// Kernel 3b (fallback if ws too small): recompute selected kv from features
__global__ __launch_bounds__(256) void recompute_kernel(
    const float* __restrict__ f, const float* __restrict__ query,
    const float* __restrict__ Wsrc, const float* __restrict__ partial,
    float* __restrict__ out) {
  int b = blockIdx.y, t = threadIdx.x;
  int hw = blockIdx.x * 256 + t;
  __shared__ float dsum[KK];
  __shared__ int scode;
  __shared__ float red[4];
  if (t < KK) {
    float s = 0.f;
    for (int x = 0; x < NBLK; x++) s += partial[((size_t)b * NBLK + x) * KK + t];
    dsum[t] = s;
  }
  __syncthreads();
  if (t == 0) {
    float best = dsum[0]; int bi = 0;
    for (int k = 1; k < KK; k++)
      if (dsum[k] < best) { best = dsum[k]; bi = k; }
    scode = bi;
    if (blockIdx.x == 0) out[OUT_SEL + b] = (float)bi;
  }
  __syncthreads();
  int code = scode;
  const float* w0 = Wsrc + (size_t)code * DQ * DIMK;
  const float* fp = f + (size_t)b * DIMK * HW + hw;
  float a0 = 0.f, a1 = 0.f, a2 = 0.f;
  for (int d = 0; d < DIMK; d++) {
    float fv = fp[(size_t)d * HW];
    a0 += w0[d] * fv;
    a1 += w0[DIMK + d] * fv;
    a2 += w0[2 * DIMK + d] * fv;
  }
  const float* qp = query + (size_t)b * DQ * HW;
  float* op = out + (size_t)b * DQ * HW;
  op[hw] = a0; op[HW + hw] = a1; op[2 * HW + hw] = a2;
  float d0 = a0 - qp[hw], d1 = a1 - qp[HW + hw], d2 = a2 - qp[2 * HW + hw];
  float lsum = d0 * d0 + d1 * d1 + d2 * d2;
  for (int off = 1; off < 64; off <<= 1) lsum += __shfl_xor(lsum, off, 64);
  if ((t & 63) == 0) red[t >> 6] = lsum;
  __syncthreads();
  if (t == 0)
    atomicAdd(&out[OUT_LOSS],
              (red[0] + red[1] + red[2] + red[3]) * (1.f / (float)(BN * DQ * HW)));
}

extern "C" void kernel_launch(void* const* d_in, const int* in_sizes, int n_in,
                              void* d_out, int out_size, void* d_ws, size_t ws_size,
                              hipStream_t stream) {
  const float* f     = (const float*)d_in[0];
  const float* query = (const float*)d_in[1];
  const float* Wsrc  = (const float*)d_in[2];
  float* out = (float*)d_out;
  char*  ws  = (char*)d_ws;

  _Float16*        A16     = (_Float16*)(ws + A16_OFF);
  float*           partial = (float*)(ws + PART_OFF);
  __hip_bfloat16*  kv      = (__hip_bfloat16*)(ws + KV_OFF);

  // Deterministic host-side branch (same every call -> graph-capture safe)
  const bool store = ws_size >= (size_t)KV_OFF + KV_BYTES;

  init_kernel<<<384, 256, 0, stream>>>(Wsrc, A16, out);
  if (store) {
    gemm_dist_kernel<true><<<dim3(NBLK, BN), 256, 0, stream>>>(f, query, A16, kv, partial);
    gather_kernel<<<BN, 256, 0, stream>>>(kv, query, partial, out);
  } else {
    gemm_dist_kernel<false><<<dim3(NBLK, BN), 256, 0, stream>>>(f, query, A16, nullptr, partial);
    recompute_kernel<<<dim3(HW / 256, BN), 256, 0, stream>>>(f, query, Wsrc, partial, out);
  }
}